// Round 2
// baseline (252.457 us; speedup 1.0000x reference)
//
#include <hip/hip_runtime.h>
#include <math.h>

// B=8192 rows, F=3072 features, block=3.
//
// v3: persistent multi-row workgroups + register double-buffer prefetch.
// v1 (strided float4) and v2 (fully coalesced + LDS transpose) measured
// IDENTICAL (~88-92 us, 2.2 TB/s, VALUBusy 10%, nothing saturated) ->
// access pattern is not the limiter; the kernel is latency-bound: one-shot
// 1-row WGs spend ~90% of their life in a single vmcnt(0) wait with nothing
// else in flight, and 8192-WG churn keeps occupancy at 67%.
// Fix: each WG owns 4 rows; row i+1's 6 loads are issued BEFORE the wait on
// row i's data (compiler emits vmcnt(6)-style partial waits), so every wave
// keeps ~6 KB in flight continuously. 2048 WGs, one barrier per WG.
#define BATCH 8192
#define FEAT  3072
#define TPB   256
#define ROWS  4
#define NWG   (BATCH / ROWS)   // 2048
#define RS4   (FEAT / 4)       // row stride in float4 units

// Analytic log|det J| for the d=3 Moebius block:
//   T(z) = w + (1-|w|^2)(z+w)/|z+w|^2 is conformal, DT = lambda*(I-2nn^T),
//   lambda = (1-|w|^2)/|z+w|^2 = c. For y = r*T(x/r): |det J| = c^(d-1) = c^2.
//   sum log|det| = 2*ln2 * sum log2(c).

__global__ __launch_bounds__(TPB, 6)   // ~85 VGPR budget; dbuf needs ~75
void moebius_kernel(const float* __restrict__ x,
                    const float* __restrict__ w,
                    float* __restrict__ out) {
    __shared__ float swred[TPB / 64][ROWS];

    const int tid  = threadIdx.x;
    const int lane = tid & 63;
    const int wave = tid >> 6;
    // Thread owns 12 contiguous floats (4 blocks) per row.
    const size_t base = (size_t)blockIdx.x * ROWS * FEAT + 12 * tid;

    const float4* __restrict__ x4 = (const float4*)(x + base);
    const float4* __restrict__ w4 = (const float4*)(w + base);
    float4* __restrict__ y4       = (float4*)(out + base);

    // Register double buffer: [2] x {x,w} x 3 float4 = 48 VGPRs.
    float4 bx[2][3], bw[2][3];
    bx[0][0] = x4[0]; bx[0][1] = x4[1]; bx[0][2] = x4[2];
    bw[0][0] = w4[0]; bw[0][1] = w4[1]; bw[0][2] = w4[2];

    #pragma unroll   // full unroll: all [i&1] indices compile-time (no scratch)
    for (int i = 0; i < ROWS; ++i) {
        const int cur = i & 1;
        if (i + 1 < ROWS) {   // prefetch next row BEFORE waiting on this one
            const int nxt = cur ^ 1;
            const int o = (i + 1) * RS4;
            bx[nxt][0] = x4[o + 0]; bx[nxt][1] = x4[o + 1]; bx[nxt][2] = x4[o + 2];
            bw[nxt][0] = w4[o + 0]; bw[nxt][1] = w4[o + 1]; bw[nxt][2] = w4[o + 2];
        }

        const float4 xa = bx[cur][0], xb = bx[cur][1], xc = bx[cur][2];
        const float4 wa = bw[cur][0], wb = bw[cur][1], wc = bw[cur][2];
        const float X[12] = {xa.x, xa.y, xa.z, xa.w, xb.x, xb.y, xb.z, xb.w,
                             xc.x, xc.y, xc.z, xc.w};
        const float W[12] = {wa.x, wa.y, wa.z, wa.w, wb.x, wb.y, wb.z, wb.w,
                             wc.x, wc.y, wc.z, wc.w};
        float Y[12];
        float lsum = 0.0f;   // accumulates log2(c)

        #pragma unroll
        for (int j = 0; j < 4; ++j) {
            const float x0 = X[3 * j], x1 = X[3 * j + 1], x2 = X[3 * j + 2];
            const float w0 = W[3 * j], w1 = W[3 * j + 1], w2 = W[3 * j + 2];

            // fmaxf guard: numerically inert for real inputs but blocks the
            // only inf->NaN path (rsq(0)=inf, 0*inf=NaN).
            const float r2   = fmaxf(x0 * x0 + x1 * x1 + x2 * x2, 1e-30f);
            const float invr = __builtin_amdgcn_rsqf(r2);   // 1/|x|
            const float r    = r2 * invr;                   // |x|

            const float p0 = x0 * invr + w0;
            const float p1 = x1 * invr + w1;
            const float p2 = x2 * invr + w2;

            const float wns  = w0 * w0 + w1 * w1 + w2 * w2;
            const float xwns = fmaxf(p0 * p0 + p1 * p1 + p2 * p2, 1e-30f);
            const float cc   = (1.0f - wns) * __builtin_amdgcn_rcpf(xwns);

            Y[3 * j]     = r * (cc * p0 + w0);
            Y[3 * j + 1] = r * (cc * p1 + w1);
            Y[3 * j + 2] = r * (cc * p2 + w2);

            lsum += __builtin_amdgcn_logf(cc);   // log2(c)
        }

        y4[i * RS4 + 0] = make_float4(Y[0], Y[1], Y[2],  Y[3]);
        y4[i * RS4 + 1] = make_float4(Y[4], Y[5], Y[6],  Y[7]);
        y4[i * RS4 + 2] = make_float4(Y[8], Y[9], Y[10], Y[11]);

        // Per-row wave reduction (no barrier); cross-wave sum deferred.
        #pragma unroll
        for (int off = 32; off > 0; off >>= 1) {
            lsum += __shfl_down(lsum, off, 64);
        }
        if (lane == 0) swred[wave][i] = lsum;
    }

    __syncthreads();   // single barrier per WG
    if (tid < ROWS) {
        const float tot = (swred[0][tid] + swred[1][tid] +
                           swred[2][tid] + swred[3][tid]) * 1.3862943611f;
        out[(size_t)BATCH * FEAT + (size_t)blockIdx.x * ROWS + tid] = tot;
    }
}

extern "C" void kernel_launch(void* const* d_in, const int* in_sizes, int n_in,
                              void* d_out, int out_size, void* d_ws, size_t ws_size,
                              hipStream_t stream) {
    const float* x = (const float*)d_in[0];
    const float* w = (const float*)d_in[1];
    float* out = (float*)d_out;   // [B*F] y followed by [B] log_det_J

    moebius_kernel<<<NWG, TPB, 0, stream>>>(x, w, out);
}